// Round 3
// baseline (741.435 us; speedup 1.0000x reference)
//
#include <hip/hip_runtime.h>

// DIAGNOSTIC ROUND: identical compute kernel to R2, launched TWICE.
// Purpose: vt_kernel has never appeared in the rocprof top-5, so its true
// duration has only ever been INFERRED as (total - biggest fill) ~= 230 us.
// That number is mechanically inexplicable (issue, latency, and RMW math all
// say we should stream at ~6.3 TB/s like the harness fill). The marginal cost
// of a second identical launch measures the kernel's real duration directly,
// independent of hidden harness reset dispatches. Writes are idempotent.
//
// out[b,t,h] = sum_{m<7} images[b,t,m] * A[m,h]

typedef float f4 __attribute__((ext_vector_type(4)));

#define NROWS  (64 * 576)   // 36864
#define HID    4096
#define MM     7
#define NW     4            // 4 windows x (256 thr x f4) = 4096 cols
#define BLOCKS 2048
#define RPB    18           // rows per block: 36864 / 2048, contiguous slice
#define SUB    6            // rows per x-load group

__global__ __launch_bounds__(256, 3) void vt_kernel(const float* __restrict__ images,
                                                    const float* __restrict__ A,
                                                    float* __restrict__ out) {
    const int tid  = threadIdx.x;
    const int row0 = blockIdx.x * RPB;

    f4 a[NW][MM];
#pragma unroll
    for (int it = 0; it < NW; ++it) {
#pragma unroll
        for (int m = 0; m < MM; ++m) {
            a[it][m] = *(const f4*)(A + (size_t)m * HID + (it << 10) + (tid << 2));
        }
    }

    for (int g = 0; g < RPB / SUB; ++g) {
        const int r0 = row0 + g * SUB;

        float x[SUB][MM];
#pragma unroll
        for (int r = 0; r < SUB; ++r) {
#pragma unroll
            for (int m = 0; m < MM; ++m) {
                x[r][m] = images[(size_t)(r0 + r) * MM + m];
            }
        }

#pragma unroll
        for (int r = 0; r < SUB; ++r) {
            float* orow = out + (size_t)(r0 + r) * HID + (tid << 2);
#pragma unroll
            for (int it = 0; it < NW; ++it) {
                f4 acc = x[r][0] * a[it][0];
#pragma unroll
                for (int m = 1; m < MM; ++m) {
                    acc += x[r][m] * a[it][m];
                }
                *(f4*)(orow + (it << 10)) = acc;
            }
        }
    }
}

extern "C" void kernel_launch(void* const* d_in, const int* in_sizes, int n_in,
                              void* d_out, int out_size, void* d_ws, size_t ws_size,
                              hipStream_t stream) {
    const float* images = (const float*)d_in[0];
    const float* A      = (const float*)d_in[1];
    float* out          = (float*)d_out;

    // Two identical, idempotent launches: marginal cost of the 2nd = true kernel time.
    vt_kernel<<<BLOCKS, 256, 0, stream>>>(images, A, out);
    vt_kernel<<<BLOCKS, 256, 0, stream>>>(images, A, out);
}

// Round 5
// 625.155 us; speedup vs baseline: 1.1860x; 1.1860x over previous
//
#include <hip/hip_runtime.h>

// out[b,t,h] = sum_{m<7} images[b,t,m] * A[m,h]
// images: (64,576,7) fp32   A: (4096,4096) fp32 (first 7 rows used)
// out:    (64,576,4096) fp32 -- 604 MB pure write stream.
//
// R5 == R4 resubmitted (R4 bench died on container acquisition, not on the
// kernel). Measured truth (R3 double-launch): kernel = 119 us = 5.1 TB/s vs
// the harness fill's 6.26 TB/s; harness fixed cost ~504 us. Attacks the 19%
// store-path gap: (1) nt stores (R0, the only nt kernel, back-solves to
// ~106 us: skip L2 dirty-writeback for a 604MB >> 32MB stream), (2) zero
// store-drain loop: coeffs committed to SGPRs via readfirstlane, next group
// PREFETCHED before the store burst so every waitcnt retires only loads older
// than all outstanding stores (vmcnt is in-order), (3) 2 A-windows/block
// (56 VGPR) instead of 4 (112) -> 4+ waves/SIMD of store MLP.

typedef float f4 __attribute__((ext_vector_type(4)));

#define NROWS  (64 * 576)        // 36864
#define HID    4096
#define MM     7
#define RPB    18                // contiguous rows per slot
#define SUB    6                 // rows per coeff group
#define NG     (RPB / SUB)       // 3
#define SLOTS  (NROWS / RPB)     // 2048
#define BLOCKS (SLOTS * 2)       // 4096: x2 column halves

__global__ __launch_bounds__(256, 4) void vt_kernel(const float* __restrict__ images,
                                                    const float* __restrict__ A,
                                                    float* __restrict__ out) {
    const int tid  = threadIdx.x;
    const int slot = (int)blockIdx.x >> 1;
    const int half = (int)blockIdx.x & 1;
    const int row0 = slot * RPB;
    const int c0   = (half << 11) + (tid << 2);   // window-0 col; window-1 at +1024

    // Two 1024-col A windows in registers (56 VGPRs), loaded once per block.
    f4 a0[MM], a1[MM];
#pragma unroll
    for (int m = 0; m < MM; ++m) {
        a0[m] = *(const f4*)(A + (size_t)m * HID + c0);
        a1[m] = *(const f4*)(A + (size_t)m * HID + c0 + 1024);
    }

    // Prologue: issue group 0's 42 uniform coeff loads (broadcast address).
    float xv[SUB * MM];
    {
        const float* ip = images + (size_t)row0 * MM;
#pragma unroll
        for (int i = 0; i < SUB * MM; ++i) xv[i] = ip[i];
    }

#pragma unroll
    for (int g = 0; g < NG; ++g) {
        // Commit coeffs to SGPRs. This waitcnt retires loads issued a full
        // group ago -- older (in vmcnt order) than every outstanding store --
        // so it never forces a store drain.
        float xs[SUB * MM];
#pragma unroll
        for (int i = 0; i < SUB * MM; ++i)
            xs[i] = __int_as_float(__builtin_amdgcn_readfirstlane(__float_as_int(xv[i])));

        // Prefetch next group's coeffs BEFORE the store burst (reuses xv regs).
        if (g + 1 < NG) {
            const float* ip = images + (size_t)(row0 + (g + 1) * SUB) * MM;
#pragma unroll
            for (int i = 0; i < SUB * MM; ++i) xv[i] = ip[i];
        }

        // 12 back-to-back nt wave-stores (6 rows x 2 windows), no loads between.
        float* orow = out + (size_t)(row0 + g * SUB) * HID + c0;
#pragma unroll
        for (int r = 0; r < SUB; ++r) {
            const int xb = r * MM;
            f4 acc0 = xs[xb] * a0[0];
            f4 acc1 = xs[xb] * a1[0];
#pragma unroll
            for (int m = 1; m < MM; ++m) {
                acc0 += xs[xb + m] * a0[m];
                acc1 += xs[xb + m] * a1[m];
            }
            __builtin_nontemporal_store(acc0, (f4*)orow);
            __builtin_nontemporal_store(acc1, (f4*)(orow + 1024));
            orow += HID;
        }
    }
}

extern "C" void kernel_launch(void* const* d_in, const int* in_sizes, int n_in,
                              void* d_out, int out_size, void* d_ws, size_t ws_size,
                              hipStream_t stream) {
    const float* images = (const float*)d_in[0];
    const float* A      = (const float*)d_in[1];
    float* out          = (float*)d_out;

    vt_kernel<<<BLOCKS, 256, 0, stream>>>(images, A, out);
}